// Round 5
// baseline (3699.137 us; speedup 1.0000x reference)
//
#include <hip/hip_runtime.h>

#define B_ 64
#define TT 1024
#define HH 256

__device__ __forceinline__ float sigmoidf_(float x) { return 1.f / (1.f + __expf(-x)); }
__device__ __forceinline__ float fast_tanh(float x) {
    float e = __expf(2.f * x);
    return 1.f - 2.f / (e + 1.f);
}

// ---------------------------------------------------------------------------
// xgemm: out[M'][1024] = A'[M'][K] @ W[1024][K]^T + (bih+bhh)
// A' row m -> (b = m>>LC, tc = m&CM), element k at
//   A[((b*RINGA + slot)*K + k)*astr]   (astr=2 skips the tag lanes of hring).
// Tile 128x128, 256 threads, 8x8 outputs/thread.
// ---------------------------------------------------------------------------
__global__ __launch_bounds__(256) void xgemm_kernel(
    const float* __restrict__ A, const float* __restrict__ W,
    const float* __restrict__ bih, const float* __restrict__ bhh,
    float* __restrict__ out,
    int K, int RINGA, int s0A, int LC, int astr)
{
    __shared__ float As[16][132];
    __shared__ float Bs[16][132];
    const int tid = threadIdx.x;
    const int bm = (int)blockIdx.x >> 3;
    const int bn = (int)blockIdx.x & 7;
    const int m0 = bm << 7, n0 = bn << 7;
    const int ty = tid >> 4, tx = tid & 15;
    const int CM = (1 << LC) - 1;

    const float* arow[8];
    const float* brow[8];
#pragma unroll
    for (int i = 0; i < 8; ++i) {
        int mm = m0 + i * 16 + ty;
        int bb = mm >> LC, tc = mm & CM;
        int slot = s0A + tc; if (slot >= RINGA) slot -= RINGA;
        arow[i] = A + ((size_t)bb * RINGA + slot) * K * astr + tx * astr;
        brow[i] = W + (size_t)(n0 + i * 16 + ty) * K + tx;
    }

    float acc[8][8];
#pragma unroll
    for (int i = 0; i < 8; ++i)
#pragma unroll
        for (int j = 0; j < 8; ++j) acc[i][j] = 0.f;

    for (int kc = 0; kc < K; kc += 16) {
#pragma unroll
        for (int i = 0; i < 8; ++i) {
            As[tx][i * 16 + ty] = arow[i][kc * astr];
            Bs[tx][i * 16 + ty] = brow[i][kc];
        }
        __syncthreads();
#pragma unroll
        for (int k = 0; k < 16; ++k) {
            float a[8], bf[8];
#pragma unroll
            for (int j = 0; j < 8; ++j) a[j] = As[k][ty * 8 + j];
#pragma unroll
            for (int j = 0; j < 8; ++j) bf[j] = Bs[k][tx * 8 + j];
#pragma unroll
            for (int i = 0; i < 8; ++i)
#pragma unroll
                for (int j = 0; j < 8; ++j) acc[i][j] = fmaf(a[i], bf[j], acc[i][j]);
        }
        __syncthreads();
    }

    float bias[8];
#pragma unroll
    for (int j = 0; j < 8; ++j) bias[j] = bih[n0 + tx * 8 + j] + bhh[n0 + tx * 8 + j];
#pragma unroll
    for (int i = 0; i < 8; ++i) {
        float4 v0 = make_float4(acc[i][0] + bias[0], acc[i][1] + bias[1],
                                acc[i][2] + bias[2], acc[i][3] + bias[3]);
        float4 v1 = make_float4(acc[i][4] + bias[4], acc[i][5] + bias[5],
                                acc[i][6] + bias[6], acc[i][7] + bias[7]);
        size_t o = (size_t)(m0 + ty * 8 + i) * 1024 + n0 + tx * 8;
        *(float4*)&out[o] = v0;
        *(float4*)&out[o + 4] = v1;
    }
}

// ---------------------------------------------------------------------------
// Persistent-per-chunk recurrence. 256 WGs = 64 batch x 4 quads; WG owns 64
// hidden dims = 256 gate rows x 256 cols of W_hh. 512 threads: thread
// (r = w*32+(l&31), hf = l>>5) holds 128 weights (32 float4 = 128 VGPR).
// amdgpu_waves_per_eu(2,2) pins the VGPR budget at 256 (no occupancy
// chasing); the GEMV is split into 4 groups of 8 ds_read_b128 separated by
// sched_barrier(0) so peak transient pressure stays ~190 < 256 -> the
// weights can stay register-resident (round 3/4 spilled at peak ~150/256+).
// Cross-quad exchange: tagged 8-byte words (tag<<32|f32bits) via relaxed
// agent-scope atomics through LLC; consumer polls its own word until tag==t.
// LDS h buffer padded +4 floats per 64-block -> conflict-free ds_read_b128.
// ---------------------------------------------------------------------------
__global__ __launch_bounds__(512)
__attribute__((amdgpu_waves_per_eu(2, 2)))
void recur_chunk(
    const float* __restrict__ xg,             // [B][CHUNK][1024]
    const float* __restrict__ Whh,            // [1024][256]
    unsigned long long* __restrict__ hring,   // [B][RING][256] (tag,val) words
    float* __restrict__ cstate,               // [256][64]
    int t0, int nsteps, int s0, int RING, int LC, int first)
{
    const int tid = threadIdx.x;
    const int b = (int)blockIdx.x & 63;
    const int q = (int)blockIdx.x >> 6;
    const int w = tid >> 6;                 // wave 0..7
    const int l = tid & 63;
    const int hf = l >> 5;                  // column half 0/1
    const int r = (w << 5) + (l & 31);      // local gate row 0..255
    const int gr = ((r >> 6) << 8) + (q << 6) + (r & 63); // global gate row

    __shared__ __align__(16) float sh_h[272];   // h idx -> idx + (idx>>6)*4
    __shared__ float sh_gate[256];

    // 128 weight floats per thread, register-resident.
    float4 w4[32];
    {
        const float4* src = (const float4*)(Whh + (size_t)gr * 256 + (hf << 7));
#pragma unroll
        for (int j = 0; j < 32; ++j) w4[j] = src[j];
    }
    // Pin in 4 statements (32 operands each) so loads can't be sunk/remat'd.
#pragma unroll
    for (int j = 0; j < 8; ++j)
        asm volatile("" : "+v"(w4[j].x), "+v"(w4[j].y), "+v"(w4[j].z), "+v"(w4[j].w));
#pragma unroll
    for (int j = 8; j < 16; ++j)
        asm volatile("" : "+v"(w4[j].x), "+v"(w4[j].y), "+v"(w4[j].z), "+v"(w4[j].w));
#pragma unroll
    for (int j = 16; j < 24; ++j)
        asm volatile("" : "+v"(w4[j].x), "+v"(w4[j].y), "+v"(w4[j].z), "+v"(w4[j].w));
#pragma unroll
    for (int j = 24; j < 32; ++j)
        asm volatile("" : "+v"(w4[j].x), "+v"(w4[j].y), "+v"(w4[j].z), "+v"(w4[j].w));

    const size_t hbB = (size_t)b * RING;
    float c = 0.f;
    if (!first && tid < 64) c = cstate[((int)blockIdx.x << 6) + tid];
    if (tid < 272) sh_h[tid] = 0.f;
    if (!first && tid < 256) {
        int sprev = (s0 == 0) ? RING - 1 : s0 - 1;
        unsigned long long v = hring[(hbB + sprev) * 256 + tid];
        sh_h[tid + ((tid >> 6) << 2)] = __uint_as_float((unsigned)v);
    }
    __syncthreads();

    // Two contiguous 64-float blocks per column half (pad breaks at 64).
    const float4* h4a = (const float4*)(sh_h + hf * 136);
    const float4* h4b = (const float4*)(sh_h + hf * 136 + 68);
    const float* xgp = xg + ((size_t)(b << LC) << 10) + gr;

    float xgv = (hf == 0) ? xgp[0] : 0.f;

    for (int tc = 0; tc < nsteps; ++tc) {
        const int t = t0 + tc;
        int slot = s0 + tc; if (slot >= RING) slot -= RING;
        const size_t srow = (hbB + slot) * 256;

        // Prefetch next step's xg value (hides ~900cy HBM latency).
        float xgn = 0.f;
        if (hf == 0 && tc + 1 < nsteps) xgn = xgp[(size_t)(tc + 1) << 10];

        float acc = 0.f;
#pragma unroll
        for (int j = 0; j < 8; ++j) {
            float4 hv = h4a[j], wv = w4[j];
            acc = fmaf(wv.x, hv.x, acc); acc = fmaf(wv.y, hv.y, acc);
            acc = fmaf(wv.z, hv.z, acc); acc = fmaf(wv.w, hv.w, acc);
        }
        __builtin_amdgcn_sched_barrier(0);
#pragma unroll
        for (int j = 8; j < 16; ++j) {
            float4 hv = h4a[j], wv = w4[j];
            acc = fmaf(wv.x, hv.x, acc); acc = fmaf(wv.y, hv.y, acc);
            acc = fmaf(wv.z, hv.z, acc); acc = fmaf(wv.w, hv.w, acc);
        }
        __builtin_amdgcn_sched_barrier(0);
#pragma unroll
        for (int j = 0; j < 8; ++j) {
            float4 hv = h4b[j], wv = w4[16 + j];
            acc = fmaf(wv.x, hv.x, acc); acc = fmaf(wv.y, hv.y, acc);
            acc = fmaf(wv.z, hv.z, acc); acc = fmaf(wv.w, hv.w, acc);
        }
        __builtin_amdgcn_sched_barrier(0);
#pragma unroll
        for (int j = 8; j < 16; ++j) {
            float4 hv = h4b[j], wv = w4[16 + j];
            acc = fmaf(wv.x, hv.x, acc); acc = fmaf(wv.y, hv.y, acc);
            acc = fmaf(wv.z, hv.z, acc); acc = fmaf(wv.w, hv.w, acc);
        }
        __builtin_amdgcn_sched_barrier(0);

        acc += __shfl_xor(acc, 32);
        if (hf == 0) sh_gate[r] = acc + xgv;
        xgv = xgn;
        __syncthreads();

        if (w == 0) {  // wave 0: gate update for our 64 hidden dims
            float gi = sh_gate[l];
            float gf = sh_gate[64 + l];
            float gg = sh_gate[128 + l];
            float go = sh_gate[192 + l];
            float i_ = sigmoidf_(gi);
            float f_ = sigmoidf_(gf);
            float g_ = fast_tanh(gg);
            float o_ = sigmoidf_(go);
            c = fmaf(f_, c, i_ * g_);
            float hn = o_ * fast_tanh(c);
            sh_h[q * 68 + l] = hn;
            unsigned long long word =
                ((unsigned long long)(unsigned)t << 32) | __float_as_uint(hn);
            __hip_atomic_store(&hring[srow + (q << 6) + l], word,
                               __ATOMIC_RELAXED, __HIP_MEMORY_SCOPE_AGENT);
        } else if (w <= 3) {  // waves 1..3: fetch one peer slice each
            const int p = (q + w) & 3;
            unsigned long long* src = &hring[srow + (p << 6) + l];
            unsigned long long v;
            for (;;) {
                v = __hip_atomic_load(src, __ATOMIC_RELAXED,
                                      __HIP_MEMORY_SCOPE_AGENT);
                if ((int)(v >> 32) == t) break;
                __builtin_amdgcn_s_sleep(1);
            }
            sh_h[p * 68 + l] = __uint_as_float((unsigned)v);
        }
        __syncthreads();
    }

    if (tid < 64) cstate[((int)blockIdx.x << 6) + tid] = c;
}

// ---------------------------------------------------------------------------
__global__ void fc_kernel(const unsigned long long* __restrict__ h2r,
                          int slot_last, int RING,
                          const float* __restrict__ fcw, const float* __restrict__ fcb,
                          float* __restrict__ out)
{
    int b = threadIdx.x;
    if (b < 64) {
        const unsigned long long* h = h2r + ((size_t)b * RING + slot_last) * 256;
        float acc = 0.f;
        for (int d = 0; d < HH; ++d)
            acc = fmaf(__uint_as_float((unsigned)h[d]), fcw[d], acc);
        out[b] = acc + fcb[0];
    }
}

extern "C" void kernel_launch(void* const* d_in, const int* in_sizes, int n_in,
                              void* d_out, int out_size, void* d_ws, size_t ws_size,
                              hipStream_t stream)
{
    const float* x     = (const float*)d_in[0];   // [64][1024][64]
    const float* W_ih0 = (const float*)d_in[1];   // [1024][64]
    const float* W_hh0 = (const float*)d_in[2];   // [1024][256]
    const float* b_ih0 = (const float*)d_in[3];
    const float* b_hh0 = (const float*)d_in[4];
    const float* W_ih1 = (const float*)d_in[5];   // [1024][256]
    const float* W_hh1 = (const float*)d_in[6];   // [1024][256]
    const float* b_ih1 = (const float*)d_in[7];
    const float* b_hh1 = (const float*)d_in[8];
    const float* fc_w  = (const float*)d_in[9];   // [1][256]
    const float* fc_b  = (const float*)d_in[10];  // [1]
    float* out = (float*)d_out;

    // Workspace-adaptive chunk size (deterministic across calls).
    auto need = [](size_t CH) -> size_t {
        return 4ull * (65536ull * CH            // xgc [64][CH][1024] f32
                     + 65536ull * (CH + 1)      // h1r+h2r rings, 8B words
                     + 32768ull);               // cstate x2
    };
    int CHUNK = 32, LC = 5;
    if      (ws_size >= need(256)) { CHUNK = 256; LC = 8; }
    else if (ws_size >= need(128)) { CHUNK = 128; LC = 7; }
    else if (ws_size >= need(64))  { CHUNK = 64;  LC = 6; }
    const int RING = CHUNK + 1;

    float* ws  = (float*)d_ws;
    float* xgc = ws;                                        // 65536*CHUNK f32
    unsigned long long* h1r =
        (unsigned long long*)(xgc + 65536ull * CHUNK);      // 16384*RING u64
    unsigned long long* h2r = h1r + 16384ull * RING;        // 16384*RING u64
    float* c0 = (float*)(h2r + 16384ull * RING);            // 16384 f32
    float* c1 = c0 + 16384;                                 // 16384 f32

    const int nchunks = TT / CHUNK;
    const int gemmblk = (B_ * CHUNK / 128) * 8;

    for (int k = 0; k < nchunks; ++k) {
        const int t0 = k * CHUNK;
        const int s0 = t0 % RING;
        const int first = (k == 0) ? 1 : 0;

        // Layer 0 input GEMM: A = x (plain f32, no ring, astr=1)
        xgemm_kernel<<<dim3(gemmblk), dim3(256), 0, stream>>>(
            x, W_ih0, b_ih0, b_hh0, xgc, 64, TT, t0, LC, 1);
        recur_chunk<<<dim3(256), dim3(512), 0, stream>>>(
            xgc, W_hh0, h1r, c0, t0, CHUNK, s0, RING, LC, first);

        // Layer 1 input GEMM: A = h1 ring (tagged pairs, astr=2)
        xgemm_kernel<<<dim3(gemmblk), dim3(256), 0, stream>>>(
            (const float*)h1r, W_ih1, b_ih1, b_hh1, xgc, 256, RING, s0, LC, 2);
        recur_chunk<<<dim3(256), dim3(512), 0, stream>>>(
            xgc, W_hh1, h2r, c1, t0, CHUNK, s0, RING, LC, first);
    }

    const int slot_last = (TT - 1) % RING;
    fc_kernel<<<dim3(1), dim3(64), 0, stream>>>(h2r, slot_last, RING, fc_w, fc_b, out);
}